// Round 9
// baseline (214.726 us; speedup 1.0000x reference)
//
#include <hip/hip_runtime.h>
#include <hip/hip_bf16.h>
#include <hip/hip_fp16.h>
#include <stdint.h>

// ---------------------------------------------------------------------------
// CLIPAttentionPooling. R18 (= R17 resubmit after infra failure + XCD remap).
// R17 re-analysis: b128 wave64 reads are structurally 8 cy (8 words/bank min);
// the 4.19M conflict counter is baseline, not fixable. The real stall theory:
// stage loads served from L3 (FETCH 41.8MB vs 16MB unique => panels not
// L2-resident under round-robin dispatch) -> vmcnt waits eat ~60% MFMA idle.
// Fix: T1 XCD-aware remap. s_stats: XCD x owns col-blocks {4x..4x+3} for all
// rows -> B-panels 1MB L2-resident per XCD; A 4x reuse. proj: 2 cols/XCD.
// Everything else identical to R17 (R15 3-phase loop + exact chunk rotate;
// R16 av). Pure index remap => absmax identical.
// ---------------------------------------------------------------------------

using half8   = __attribute__((ext_vector_type(8))) _Float16;
using float4v = __attribute__((ext_vector_type(4))) float;
using int4v   = __attribute__((ext_vector_type(4))) int;
using uint2v  = __attribute__((ext_vector_type(2))) unsigned int;

// q/k int16 grid: covers +-6.0, v = QS*(256*hi+lo)
#define QS        (6.0f / 32768.0f)
#define INV_S     (32768.0f / 6.0f)
#define INV_S256  (128.0f / 6.0f)
#define C_HH      (65536.0f * QS * QS)
#define C_X       (256.0f * QS * QS)

// x grid: +-6.0 ; W grid: +-0.25
#define SX        (6.0f / 32768.0f)
#define SW        (0.25f / 32768.0f)
#define P_HH      (65536.0f * SX * SW)
#define P_X       (256.0f * SX * SW)

#define GLOAD_LDS16(gptr, ldsptr)                                              \
  __builtin_amdgcn_global_load_lds(                                            \
      (__attribute__((address_space(1))) void*)(uintptr_t)(gptr),              \
      (__attribute__((address_space(3))) void*)(unsigned)(uintptr_t)(ldsptr),  \
      16, 0, 0)

__device__ __forceinline__ void barrier_raw() {
  asm volatile("" ::: "memory");
  __builtin_amdgcn_s_barrier();
  asm volatile("" ::: "memory");
}

// chunk-level swizzle for the epilogue images (R12-proven).
__device__ __forceinline__ int swz3(int row) {
  return (((row >> 2) & 3) << 1) ^ (row & 3);
}

// ---------------------------------------------------------------------------
// S GEMM + tile softmax stats. Split-i8 16x16x64, 128x128 tile, BK=64.
// R15 3-phase K-step + chunk rotate + R18 XCD col-group remap.
__global__ __launch_bounds__(256, 2) void gemm_s_stats(
    const int8_t* __restrict__ Ahi, const int8_t* __restrict__ Alo,
    const int8_t* __restrict__ Bhi, const int8_t* __restrict__ Blo,
    _Float16* __restrict__ E, float2* __restrict__ stats)
{
  __shared__ __align__(16) int8_t smem[65536];
  int8_t* sAh = smem;            // [2][8192]
  int8_t* sAl = smem + 16384;    // [2][8192]
  int8_t* sBh = smem + 32768;    // [2][8192]
  int8_t* sBl = smem + 49152;    // [2][8192]

  const int tid  = threadIdx.x;
  const int wave = tid >> 6;
  const int lane = tid & 63;
  const int quad = lane >> 4;
  const int t16  = lane & 15;
  const int wm   = wave & 1;
  const int wn   = wave >> 1;

  // XCD remap: XCD x owns col-blocks {4x..4x+3}, all 32 row-blocks.
  const int L    = blockIdx.y * 32 + blockIdx.x;  // 0..1023
  const int xcd  = L & 7;
  const int idx  = L >> 3;                        // 0..127
  const int bx   = xcd * 4 + (idx & 3);           // col-block 0..31
  const int by   = idx >> 2;                      // row-block 0..31
  const int row0 = by * 128;
  const int col0 = bx * 128;

  const int seg  = lane & 3;   // LDS chunk slot this lane fills
  const int rsub = lane >> 2;  // row within 16-row stripe
  const int segS = (seg - rsub) & 3;  // global chunk sourced (rotate)
  const int rch  = ((quad + t16) & 3) * 16;  // read chunk byte offset

  const int offA0 = (row0 + wave * 16 + rsub) * 2048 + segS * 16;
  const int offA1 = offA0 + 64 * 2048;
  const int offB0 = (col0 + wave * 16 + rsub) * 2048 + segS * 16;
  const int offB1 = offB0 + 64 * 2048;
  const int ldsT0 = (wave * 16) * 64;
  const int ldsT1 = (64 + wave * 16) * 64;

  int4v hh[4][4], cc[4][4];
#pragma unroll
  for (int i = 0; i < 4; ++i)
#pragma unroll
    for (int j = 0; j < 4; ++j) {
      hh[i][j] = (int4v){0, 0, 0, 0};
      cc[i][j] = (int4v){0, 0, 0, 0};
    }

  auto stage_AhBh = [&](int ks, int b) {
    const int k0 = ks * 64;
    GLOAD_LDS16(Ahi + offA0 + k0, sAh + b * 8192 + ldsT0);
    GLOAD_LDS16(Ahi + offA1 + k0, sAh + b * 8192 + ldsT1);
    GLOAD_LDS16(Bhi + offB0 + k0, sBh + b * 8192 + ldsT0);
    GLOAD_LDS16(Bhi + offB1 + k0, sBh + b * 8192 + ldsT1);
  };
  auto stage_Bl = [&](int ks, int b) {
    const int k0 = ks * 64;
    GLOAD_LDS16(Blo + offB0 + k0, sBl + b * 8192 + ldsT0);
    GLOAD_LDS16(Blo + offB1 + k0, sBl + b * 8192 + ldsT1);
  };
  auto stage_Al = [&](int ks, int b) {
    const int k0 = ks * 64;
    GLOAD_LDS16(Alo + offA0 + k0, sAl + b * 8192 + ldsT0);
    GLOAD_LDS16(Alo + offA1 + k0, sAl + b * 8192 + ldsT1);
  };

  stage_AhBh(0, 0);
  stage_Bl(0, 0);
  stage_Al(0, 0);

  int buf = 0;
  for (int ks = 0; ks < 16; ++ks) {
    // ---- P1: hh pass ----
    asm volatile("s_waitcnt vmcnt(4)" ::: "memory");
    barrier_raw();
    if (ks < 15) stage_AhBh(ks + 1, buf ^ 1);

    int4v ah[4], bh[4];
#pragma unroll
    for (int i = 0; i < 4; ++i)
      ah[i] = *(const int4v*)(sAh + buf * 8192 +
                              (wm * 64 + i * 16 + t16) * 64 + rch);
#pragma unroll
    for (int j = 0; j < 4; ++j)
      bh[j] = *(const int4v*)(sBh + buf * 8192 +
                              (wn * 64 + j * 16 + t16) * 64 + rch);

    __builtin_amdgcn_s_setprio(1);
#pragma unroll
    for (int i = 0; i < 4; ++i)
#pragma unroll
      for (int j = 0; j < 4; ++j)
        hh[i][j] = __builtin_amdgcn_mfma_i32_16x16x64_i8(ah[i], bh[j], hh[i][j], 0, 0, 0);
    __builtin_amdgcn_s_setprio(0);

    // ---- P2: cc pass 1 (ah * bl) ----
    if (ks < 15) asm volatile("s_waitcnt vmcnt(6)" ::: "memory");
    else         asm volatile("s_waitcnt vmcnt(2)" ::: "memory");
    barrier_raw();
    if (ks < 15) stage_Bl(ks + 1, buf ^ 1);

    int4v bl[4];
#pragma unroll
    for (int j = 0; j < 4; ++j)
      bl[j] = *(const int4v*)(sBl + buf * 8192 +
                              (wn * 64 + j * 16 + t16) * 64 + rch);

    __builtin_amdgcn_s_setprio(1);
#pragma unroll
    for (int i = 0; i < 4; ++i)
#pragma unroll
      for (int j = 0; j < 4; ++j)
        cc[i][j] = __builtin_amdgcn_mfma_i32_16x16x64_i8(ah[i], bl[j], cc[i][j], 0, 0, 0);
    __builtin_amdgcn_s_setprio(0);

    // ---- P3: cc pass 2 (al * bh) ----
    if (ks < 15) asm volatile("s_waitcnt vmcnt(6)" ::: "memory");
    else         asm volatile("s_waitcnt vmcnt(0)" ::: "memory");
    barrier_raw();
    if (ks < 15) stage_Al(ks + 1, buf ^ 1);

    int4v al[4];
#pragma unroll
    for (int i = 0; i < 4; ++i)
      al[i] = *(const int4v*)(sAl + buf * 8192 +
                              (wm * 64 + i * 16 + t16) * 64 + rch);

    __builtin_amdgcn_s_setprio(1);
#pragma unroll
    for (int i = 0; i < 4; ++i)
#pragma unroll
      for (int j = 0; j < 4; ++j)
        cc[i][j] = __builtin_amdgcn_mfma_i32_16x16x64_i8(al[i], bh[j], cc[i][j], 0, 0, 0);
    __builtin_amdgcn_s_setprio(0);

    buf ^= 1;
  }

  // ---- epilogue: tile-local softmax stats + LDS-image E store -------------
  float* red = (float*)smem;  // buf-0 Ahi region; step-15 reads were buf 1

  float vv[4][4][4];
  float rmax[4][4];
#pragma unroll
  for (int i = 0; i < 4; ++i)
#pragma unroll
    for (int r = 0; r < 4; ++r) {
      float mx = -3.0e38f;
#pragma unroll
      for (int j = 0; j < 4; ++j) {
        float v = C_HH * (float)hh[i][j][r] + C_X * (float)cc[i][j][r];
        vv[i][j][r] = v;
        mx = fmaxf(mx, v);
      }
      mx = fmaxf(mx, __shfl_xor(mx, 1));
      mx = fmaxf(mx, __shfl_xor(mx, 2));
      mx = fmaxf(mx, __shfl_xor(mx, 4));
      mx = fmaxf(mx, __shfl_xor(mx, 8));
      rmax[i][r] = mx;
    }
  if (t16 == 0) {
#pragma unroll
    for (int i = 0; i < 4; ++i)
#pragma unroll
      for (int r = 0; r < 4; ++r)
        red[wn * 128 + wm * 64 + i * 16 + quad * 4 + r] = rmax[i][r];
  }
  __syncthreads();

  float mrow[4][4];
#pragma unroll
  for (int i = 0; i < 4; ++i)
#pragma unroll
    for (int r = 0; r < 4; ++r) {
      const int row = wm * 64 + i * 16 + quad * 4 + r;
      mrow[i][r] = fmaxf(red[row], red[128 + row]);
    }

  float rsum[4][4];
#pragma unroll
  for (int i = 0; i < 4; ++i)
#pragma unroll
    for (int r = 0; r < 4; ++r) {
      float s = 0.f;
#pragma unroll
      for (int j = 0; j < 4; ++j) {
        float e = __expf(vv[i][j][r] - mrow[i][r]);
        vv[i][j][r] = e;
        s += e;
      }
      s += __shfl_xor(s, 1);
      s += __shfl_xor(s, 2);
      s += __shfl_xor(s, 4);
      s += __shfl_xor(s, 8);
      rsum[i][r] = s;
    }
  if (t16 == 0) {
#pragma unroll
    for (int i = 0; i < 4; ++i)
#pragma unroll
      for (int r = 0; r < 4; ++r)
        red[256 + wn * 128 + wm * 64 + i * 16 + quad * 4 + r] = rsum[i][r];
  }

  // E fragments -> swizzled u16 image (overlays sBh/sBl: dead after K loop)
  uint16_t* img = (uint16_t*)(smem + 32768);  // [128][128] u16 = 32 KB
#pragma unroll
  for (int i = 0; i < 4; ++i)
#pragma unroll
    for (int j = 0; j < 4; ++j)
#pragma unroll
      for (int r = 0; r < 4; ++r) {
        const int row  = wm * 64 + i * 16 + quad * 4 + r;
        const int col  = wn * 64 + j * 16 + t16;
        const int colS = col ^ (((quad << 1) ^ r) << 3);
        _Float16 h = (_Float16)vv[i][j][r];
        img[row * 128 + colS] = *(const uint16_t*)&h;
      }
  __syncthreads();  // covers red-sum writes AND img writes

  // coalesced E store: 8 x b128 per thread
#pragma unroll
  for (int it = 0; it < 8; ++it) {
    const int row    = wave * 32 + it * 4 + quad;
    const int chunkS = t16 ^ swz3(row);
    int4v v = *(const int4v*)&img[row * 128 + chunkS * 8];
    *(int4v*)&E[(size_t)(row0 + row) * 4096 + col0 + t16 * 8] = v;
  }

  if (wn == 0 && t16 == 0) {
#pragma unroll
    for (int i = 0; i < 4; ++i)
#pragma unroll
      for (int r = 0; r < 4; ++r) {
        const int row = wm * 64 + i * 16 + quad * 4 + r;
        const float l = red[256 + row] + red[256 + 128 + row];
        stats[(size_t)(row0 + row) * 32 + bx] =
            make_float2(mrow[i][r], l);
      }
  }
}

// ---------------------------------------------------------------------------
// proj: qk = x Wqk^T + bias. R15 3-phase K-step + rotate + XCD remap.
__global__ __launch_bounds__(256, 2) void gemm_proj_i8(
    const int8_t* __restrict__ Ahi, const int8_t* __restrict__ Alo,
    const int8_t* __restrict__ Bhi, const int8_t* __restrict__ Blo,
    const float* __restrict__ biasQ, const float* __restrict__ biasK,
    int8_t* __restrict__ Ch, int8_t* __restrict__ Cl)
{
  __shared__ __align__(16) int8_t smem[65536];
  int8_t* sAh = smem;
  int8_t* sAl = smem + 16384;
  int8_t* sBh = smem + 32768;
  int8_t* sBl = smem + 49152;

  const int tid  = threadIdx.x;
  const int wave = tid >> 6;
  const int lane = tid & 63;
  const int quad = lane >> 4;
  const int t16  = lane & 15;
  const int wm   = wave & 1;
  const int wn   = wave >> 1;

  // XCD remap: XCD x owns col-blocks {2x, 2x+1}, all 32 row-blocks.
  const int L    = blockIdx.y * 16 + blockIdx.x;  // 0..511
  const int xcd  = L & 7;
  const int idx  = L >> 3;                        // 0..63
  const int bx   = xcd * 2 + (idx & 1);           // col-block 0..15
  const int by   = idx >> 1;                      // row-block 0..31
  const int row0 = by * 128;
  const int col0 = bx * 128;

  const int seg  = lane & 3;
  const int rsub = lane >> 2;
  const int segS = (seg - rsub) & 3;
  const int rch  = ((quad + t16) & 3) * 16;

  const int offA0 = (row0 + wave * 16 + rsub) * 1024 + segS * 16;
  const int offA1 = offA0 + 64 * 1024;
  const int offB0 = (col0 + wave * 16 + rsub) * 1024 + segS * 16;
  const int offB1 = offB0 + 64 * 1024;
  const int ldsT0 = (wave * 16) * 64;
  const int ldsT1 = (64 + wave * 16) * 64;

  int4v hh[4][4], cc[4][4];
#pragma unroll
  for (int i = 0; i < 4; ++i)
#pragma unroll
    for (int j = 0; j < 4; ++j) {
      hh[i][j] = (int4v){0, 0, 0, 0};
      cc[i][j] = (int4v){0, 0, 0, 0};
    }

  auto stage_AhBh = [&](int ks, int b) {
    const int k0 = ks * 64;
    GLOAD_LDS16(Ahi + offA0 + k0, sAh + b * 8192 + ldsT0);
    GLOAD_LDS16(Ahi + offA1 + k0, sAh + b * 8192 + ldsT1);
    GLOAD_LDS16(Bhi + offB0 + k0, sBh + b * 8192 + ldsT0);
    GLOAD_LDS16(Bhi + offB1 + k0, sBh + b * 8192 + ldsT1);
  };
  auto stage_Bl = [&](int ks, int b) {
    const int k0 = ks * 64;
    GLOAD_LDS16(Blo + offB0 + k0, sBl + b * 8192 + ldsT0);
    GLOAD_LDS16(Blo + offB1 + k0, sBl + b * 8192 + ldsT1);
  };
  auto stage_Al = [&](int ks, int b) {
    const int k0 = ks * 64;
    GLOAD_LDS16(Alo + offA0 + k0, sAl + b * 8192 + ldsT0);
    GLOAD_LDS16(Alo + offA1 + k0, sAl + b * 8192 + ldsT1);
  };

  stage_AhBh(0, 0);
  stage_Bl(0, 0);
  stage_Al(0, 0);

  int buf = 0;
  for (int ks = 0; ks < 16; ++ks) {
    // ---- P1 ----
    asm volatile("s_waitcnt vmcnt(4)" ::: "memory");
    barrier_raw();
    if (ks < 15) stage_AhBh(ks + 1, buf ^ 1);

    int4v ah[4], bh[4];
#pragma unroll
    for (int i = 0; i < 4; ++i)
      ah[i] = *(const int4v*)(sAh + buf * 8192 +
                              (wm * 64 + i * 16 + t16) * 64 + rch);
#pragma unroll
    for (int j = 0; j < 4; ++j)
      bh[j] = *(const int4v*)(sBh + buf * 8192 +
                              (wn * 64 + j * 16 + t16) * 64 + rch);

    __builtin_amdgcn_s_setprio(1);
#pragma unroll
    for (int i = 0; i < 4; ++i)
#pragma unroll
      for (int j = 0; j < 4; ++j)
        hh[i][j] = __builtin_amdgcn_mfma_i32_16x16x64_i8(ah[i], bh[j], hh[i][j], 0, 0, 0);
    __builtin_amdgcn_s_setprio(0);

    // ---- P2 ----
    if (ks < 15) asm volatile("s_waitcnt vmcnt(6)" ::: "memory");
    else         asm volatile("s_waitcnt vmcnt(2)" ::: "memory");
    barrier_raw();
    if (ks < 15) stage_Bl(ks + 1, buf ^ 1);

    int4v bl[4];
#pragma unroll
    for (int j = 0; j < 4; ++j)
      bl[j] = *(const int4v*)(sBl + buf * 8192 +
                              (wn * 64 + j * 16 + t16) * 64 + rch);

    __builtin_amdgcn_s_setprio(1);
#pragma unroll
    for (int i = 0; i < 4; ++i)
#pragma unroll
      for (int j = 0; j < 4; ++j)
        cc[i][j] = __builtin_amdgcn_mfma_i32_16x16x64_i8(ah[i], bl[j], cc[i][j], 0, 0, 0);
    __builtin_amdgcn_s_setprio(0);

    // ---- P3 ----
    if (ks < 15) asm volatile("s_waitcnt vmcnt(6)" ::: "memory");
    else         asm volatile("s_waitcnt vmcnt(0)" ::: "memory");
    barrier_raw();
    if (ks < 15) stage_Al(ks + 1, buf ^ 1);

    int4v al[4];
#pragma unroll
    for (int i = 0; i < 4; ++i)
      al[i] = *(const int4v*)(sAl + buf * 8192 +
                              (wm * 64 + i * 16 + t16) * 64 + rch);

    __builtin_amdgcn_s_setprio(1);
#pragma unroll
    for (int i = 0; i < 4; ++i)
#pragma unroll
      for (int j = 0; j < 4; ++j)
        cc[i][j] = __builtin_amdgcn_mfma_i32_16x16x64_i8(al[i], bh[j], cc[i][j], 0, 0, 0);
    __builtin_amdgcn_s_setprio(0);

    buf ^= 1;
  }

  // ---- epilogue: quant -> packed u16 image -> coalesced plane stores ------
  uint16_t* img = (uint16_t*)(smem + 32768);  // [128][128] u16
#pragma unroll
  for (int i = 0; i < 4; ++i) {
#pragma unroll
    for (int j = 0; j < 4; ++j) {
      const int ccol = col0 + wn * 64 + j * 16 + t16;
      const float* bp = (ccol < 1024) ? biasQ : (biasK - 1024);
#pragma unroll
      for (int r = 0; r < 4; ++r) {
        float v = P_HH * (float)hh[i][j][r] + P_X * (float)cc[i][j][r] + bp[ccol];
        int hi = (int)lrintf(v * INV_S256);
        hi = hi > 127 ? 127 : (hi < -127 ? -127 : hi);
        int lo = (int)lrintf(v * INV_S - 256.0f * (float)hi);
        lo = lo > 127 ? 127 : (lo < -127 ? -127 : lo);
        const int row  = wm * 64 + i * 16 + quad * 4 + r;
        const int col  = wn * 64 + j * 16 + t16;
        const int colS = col ^ (((quad << 1) ^ r) << 3);
        img[row * 128 + colS] = (uint16_t)((hi & 0xff) | ((lo & 0xff) << 8));
      }
    }
  }
  __syncthreads();

#pragma unroll
  for (int it = 0; it < 8; ++it) {
    const int row    = wave * 32 + it * 4 + quad;
    const int chunkS = t16 ^ swz3(row);
    int4v p = *(const int4v*)&img[row * 128 + chunkS * 8];
    const unsigned w0 = (unsigned)p[0], w1 = (unsigned)p[1];
    const unsigned w2 = (unsigned)p[2], w3 = (unsigned)p[3];
    uint2v hw, lw;
    hw[0] = (w0 & 0xffu) | (((w0 >> 16) & 0xffu) << 8) |
            ((w1 & 0xffu) << 16) | (((w1 >> 16) & 0xffu) << 24);
    hw[1] = (w2 & 0xffu) | (((w2 >> 16) & 0xffu) << 8) |
            ((w3 & 0xffu) << 16) | (((w3 >> 16) & 0xffu) << 24);
    lw[0] = ((w0 >> 8) & 0xffu) | (((w0 >> 24) & 0xffu) << 8) |
            (((w1 >> 8) & 0xffu) << 16) | ((w1 >> 24) << 24);
    lw[1] = ((w2 >> 8) & 0xffu) | (((w2 >> 24) & 0xffu) << 8) |
            (((w3 >> 8) & 0xffu) << 16) | ((w3 >> 24) << 24);
    const size_t go = (size_t)(row0 + row) * 2048 + col0 + t16 * 8;
    *(uint2v*)&Ch[go] = hw;
    *(uint2v*)&Cl[go] = lw;
  }
}

// ---------------------------------------------------------------------------
// AV: out = sum_t beta_t (E_t x). R16 version (unchanged): 512 blocks x 256
// thr, 128x64 tiles, no split-K, 2 blocks/CU, chunk-rotate swizzle.
__global__ __launch_bounds__(256, 2) void gemm_av(
    const uint16_t* __restrict__ E, const uint16_t* __restrict__ B,
    const float2* __restrict__ stats, float* __restrict__ out)
{
  // [buf][ A:128x64h | B:64x64h ] = 2 x 24 KB
  __shared__ __align__(16) uint16_t stg[2][12288];
  __shared__ _Float16 betaS[128 * 33];   // 8.25 KB

  const int L      = blockIdx.x;        // 0..511
  const int xcd    = L & 7;
  const int rest   = L >> 3;            // 0..63
  const int colb   = rest & 15;         // 0..15
  const int bandHi = rest >> 4;         // 0..3
  const int band   = xcd + 8 * bandHi;  // 0..31
  const int row0   = band * 128;
  const int col0   = colb * 64;

  const int tid  = threadIdx.x;
  const int wave = tid >> 6;            // 0..3
  const int lane = tid & 63;
  const int quad = lane >> 4;
  const int t16  = lane & 15;
  const int wm   = wave & 1;
  const int wn   = wave >> 1;

  const int r8   = lane >> 3;           // row within 8-row stripe
  const int c8   = lane & 7;            // 16B chunk within 128B row
  const int srcC = (c8 - r8) & 7;       // rotate: LDS[row][c] = glob[(c-row)&7]

  // stage offsets in halves (+ s*64 per step)
  int offA[4], offBx[2];
#pragma unroll
  for (int p = 0; p < 4; ++p)
    offA[p] = (row0 + p * 32 + wave * 8 + r8) * 4096 + srcC * 8;
#pragma unroll
  for (int p = 0; p < 2; ++p)
    offBx[p] = (col0 + p * 32 + wave * 8 + r8) * 4096 + srcC * 8;

  auto stage_s = [&](int s, int b) {
    const int k0h = s * 64;
    uint16_t* sA = &stg[b][0];
    uint16_t* sB = &stg[b][8192];
#pragma unroll
    for (int p = 0; p < 4; ++p)
      GLOAD_LDS16(E + offA[p] + k0h, &sA[(p * 32 + wave * 8) * 64]);
#pragma unroll
    for (int p = 0; p < 2; ++p)
      GLOAD_LDS16(B + offBx[p] + k0h, &sB[(p * 32 + wave * 8) * 64]);
  };

  stage_s(0, 0);  // HBM latency hides under the beta prologue

  // ---- beta prologue: threads 0..127, one row each ------------------------
  if (tid < 128) {
    const int row = row0 + tid;
    float2 st[32];
    float m = -3.0e38f;
#pragma unroll
    for (int t = 0; t < 32; ++t) {
      st[t] = stats[(size_t)row * 32 + t];
      m = fmaxf(m, st[t].x);
    }
    float l = 0.f;
#pragma unroll
    for (int t = 0; t < 32; ++t) l += st[t].y * __expf(st[t].x - m);
    const float inv = 1.0f / l;
#pragma unroll
    for (int t = 0; t < 32; ++t)
      betaS[tid * 33 + t] = (_Float16)(__expf(st[t].x - m) * inv);
  }
  asm volatile("s_waitcnt vmcnt(0)" ::: "memory");
  __syncthreads();  // covers betaS AND stage(0)

  float4v acc[4][2];
#pragma unroll
  for (int i = 0; i < 4; ++i)
#pragma unroll
    for (int j = 0; j < 2; ++j)
      acc[i][j] = (float4v){0.f, 0.f, 0.f, 0.f};

  int buf = 0;
  for (int s = 0; s < 64; ++s) {
    if (s < 63) stage_s(s + 1, buf ^ 1);

    const int t = s >> 1;
    _Float16 bb[4];
#pragma unroll
    for (int i = 0; i < 4; ++i)
      bb[i] = betaS[(wm * 64 + i * 16 + t16) * 33 + t];

    const uint16_t* sA = &stg[buf][0];
    const uint16_t* sB = &stg[buf][8192];

    half8 af[2][4], bf[2][2];
#pragma unroll
    for (int ks = 0; ks < 2; ++ks) {
#pragma unroll
      for (int i = 0; i < 4; ++i) {
        const int row = wm * 64 + i * 16 + t16;
        const int ch  = (ks * 4 + quad + (t16 & 7)) & 7;
        af[ks][i] = *(const half8*)&sA[row * 64 + ch * 8];
        half8 bs;
#pragma unroll
        for (int c = 0; c < 8; ++c) bs[c] = bb[i];
        af[ks][i] = af[ks][i] * bs;
      }
#pragma unroll
      for (int j = 0; j < 2; ++j) {
        const int row = wn * 32 + j * 16 + t16;
        const int ch  = (ks * 4 + quad + (t16 & 7)) & 7;
        bf[ks][j] = *(const half8*)&sB[row * 64 + ch * 8];
      }
    }

    __builtin_amdgcn_s_setprio(1);
#pragma unroll
    for (int ks = 0; ks < 2; ++ks)
#pragma unroll
      for (int i = 0; i < 4; ++i)
#pragma unroll
        for (int j = 0; j < 2; ++j)
          acc[i][j] = __builtin_amdgcn_mfma_f32_16x16x32_f16(af[ks][i], bf[ks][j], acc[i][j], 0, 0, 0);
    __builtin_amdgcn_s_setprio(0);

    if (s < 63) asm volatile("s_waitcnt vmcnt(0)" ::: "memory");
    barrier_raw();
    buf ^= 1;
  }

  // ---- fp32 image store (no split-K combine needed) -----------------------
  float* img = (float*)stg;  // [128][64] f32 = 32 KB over the stage region
#pragma unroll
  for (int i = 0; i < 4; ++i)
#pragma unroll
    for (int j = 0; j < 2; ++j)
#pragma unroll
      for (int r = 0; r < 4; ++r) {
        const int row  = wm * 64 + i * 16 + quad * 4 + r;
        const int col  = wn * 32 + j * 16 + t16;
        const int colS = col ^ (swz3(row) << 2);
        img[row * 64 + colS] = acc[i][j][r];
      }
  __syncthreads();

#pragma unroll
  for (int it = 0; it < 8; ++it) {
    const int row    = wave * 32 + it * 4 + quad;
    const int chunkS = t16 ^ swz3(row);      // 16 chunks of 4 floats
    float4v v = *(const float4v*)&img[row * 64 + chunkS * 4];
    *(float4v*)&out[(size_t)(row0 + row) * 1024 + col0 + t16 * 4] = v;
  }
}

// ---------------------------------------------------------------------------
// Fused quant + transpose-cast (unchanged).
__global__ __launch_bounds__(256) void quantT(
    const float* __restrict__ x, const float* __restrict__ Wq,
    const float* __restrict__ Wk,
    int8_t* __restrict__ xhi, int8_t* __restrict__ xlo,
    int8_t* __restrict__ whi, int8_t* __restrict__ wlo,
    uint16_t* __restrict__ xT)
{
  if (blockIdx.x < 6144) {
    int i = blockIdx.x * 256 + threadIdx.x;  // 0..1572863
    const float* src; int8_t* dh; int8_t* dl; int idx; float s256, s;
    if (i < 1048576)      { src = x;  idx = i;           dh = xhi; dl = xlo;
                            s256 = INV_S256; s = INV_S; }
    else if (i < 1310720) { src = Wq; idx = i - 1048576; dh = whi; dl = wlo;
                            s256 = 512.0f; s = 131072.0f; }
    else                  { src = Wk; idx = i - 1310720; dh = whi + 1048576;
                            dl = wlo + 1048576; s256 = 512.0f; s = 131072.0f; }
    float4 v = ((const float4*)src)[idx];
    float vv[4] = {v.x, v.y, v.z, v.w};
    int hp = 0, lp = 0;
#pragma unroll
    for (int c = 0; c < 4; ++c) {
      int h = (int)lrintf(vv[c] * s256);
      h = h > 127 ? 127 : (h < -127 ? -127 : h);
      int l = (int)lrintf(vv[c] * s - 256.0f * (float)h);
      l = l > 127 ? 127 : (l < -127 ? -127 : l);
      hp |= (h & 0xff) << (8 * c);
      lp |= (l & 0xff) << (8 * c);
    }
    ((int*)dh)[idx] = hp;
    ((int*)dl)[idx] = lp;
  } else {
    __shared__ float tile[32][33];
    const int tb = blockIdx.x - 6144;   // 0..4095
    const int bx = tb & 31;             // D/32
    const int by = tb >> 5;             // N/32
    const int tx = threadIdx.x & 31;
    const int ty = threadIdx.x >> 5;    // 0..7
#pragma unroll
    for (int p = 0; p < 4; ++p) {
      const int row = by * 32 + ty + p * 8;
      tile[ty + p * 8][tx] = x[(size_t)row * 1024 + bx * 32 + tx];
    }
    __syncthreads();
#pragma unroll
    for (int p = 0; p < 4; ++p) {
      const int oc = ty + p * 8;  // local col in x == local row in xT
      __half hv = __float2half_rn(tile[tx][oc]);
      xT[(size_t)(bx * 32 + oc) * 4096 + by * 32 + tx] = *(uint16_t*)&hv;
    }
  }
}

extern "C" void kernel_launch(void* const* d_in, const int* in_sizes, int n_in,
                              void* d_out, int out_size, void* d_ws, size_t ws_size,
                              hipStream_t stream) {
  const int N = 4096, D = 1024;
  const float* x  = (const float*)d_in[0];
  const float* Wq = (const float*)d_in[1];
  const float* bq = (const float*)d_in[2];
  const float* Wk = (const float*)d_in[3];
  const float* bk = (const float*)d_in[4];
  float* out = (float*)d_out;

  // workspace layout (MiB offsets)
  char* w = (char*)d_ws;
  const size_t MiB = 1024 * 1024;
  int8_t*    xq_hi  = (int8_t*)   (w + 0  * MiB);  // [N x D]
  int8_t*    xq_lo  = (int8_t*)   (w + 4  * MiB);
  int8_t*    Wqk_hi = (int8_t*)   (w + 8  * MiB);  // [2048 x D]
  int8_t*    Wqk_lo = (int8_t*)   (w + 10 * MiB);
  int8_t*    qk_hi  = (int8_t*)   (w + 12 * MiB);  // [N x 2048]
  int8_t*    qk_lo  = (int8_t*)   (w + 20 * MiB);
  _Float16*  E      = (_Float16*) (w + 36 * MiB);  // [N x N] fp16, 32 MiB
  float2*    stats  = (float2*)   (w + 68 * MiB);  // [N x 32] (m,l), 1 MiB
  uint16_t*  xTh    = (uint16_t*) (w + 72 * MiB);  // [D x N] fp16
  // total 80 MiB

  // 1) fused quantization + transpose-cast  (6144 + 4096 blocks)
  quantT<<<10240, 256, 0, stream>>>(x, Wq, Wk, xq_hi, xq_lo, Wqk_hi, Wqk_lo,
                                    xTh);

  // 2) fused qk projection: i8 16x16x64, 3-phase K-step, XCD remap
  gemm_proj_i8<<<dim3(2048 / 128, N / 128), 256, 0, stream>>>(
      xq_hi, xq_lo, Wqk_hi, Wqk_lo, bq, bk, qk_hi, qk_lo);

  // 3) S = q k^T + tile softmax stats -> E fp16, stats (m_t, l_t), XCD remap
  gemm_s_stats<<<dim3(N / 128, N / 128), 256, 0, stream>>>(
      qk_hi, qk_lo, qk_hi + 1024, qk_lo + 1024, E, stats);

  // 4) out = sum_t beta_t (E_t x): 512 blocks, 128x64 tiles, no split-K
  gemm_av<<<512, 256, 0, stream>>>((const uint16_t*)E, xTh, stats, out);

  (void)in_sizes; (void)n_in; (void)out_size; (void)ws_size;
}